// Round 13
// baseline (91.072 us; speedup 1.0000x reference)
//
#include <hip/hip_runtime.h>
#include <math.h>

#define A_    16
#define N_    1000
#define F_    16
#define E_    16000
#define D_    128
#define DP    132         // padded LDS row stride
#define CAP_  48          // max tracked in-degree (Binomial mean 16)
#define MAXS  49          // slot 0 = self, 1..48 = in-edges of agent node
#define NBP   196         // producer blocks (4 waves each = 784 = 16*49 slots)
#define NBT   16          // tail blocks (one per agent)

__device__ __forceinline__ float lrelu(float v){ return v > 0.0f ? v : 0.2f*v; }
__device__ __forceinline__ float sigm(float x){ return 1.0f/(1.0f + expf(-x)); }

// ---- D1: block 0 = LDS-histogram edge scan + zero flags; blocks 1-6 = gh;
//          blocks 7-22 = per-agent flag scan. All independent. -------------
__global__ void __launch_bounds__(1024) k_pre(
    const int* __restrict__ ei, const float* __restrict__ nf,
    const float* __restrict__ hs, const float* __restrict__ Whh,
    const float* __restrict__ bhh,
    int* __restrict__ ncount, int* __restrict__ nbrs,
    int* __restrict__ agent_node, float* __restrict__ ghb,
    int* __restrict__ flags){
  const int bid = blockIdx.x;
  const int tid = threadIdx.x;

  if (bid == 0){                       // inverted adjacency via LDS histogram
    __shared__ int lcnt[N_];
    if (tid < N_) lcnt[tid] = 0;
    if (tid >= 1000 && tid < 1016) flags[tid - 1000] = 0;
    __syncthreads();
    #pragma unroll
    for (int q = 0; q < 16; ++q){
      const int e = q*1024 + tid;
      if (e < E_){
        int src = ei[e], dst = ei[E_ + e];
        int pos = atomicAdd(&lcnt[dst], 1);
        if (pos < CAP_) nbrs[dst*CAP_ + pos] = src;
      }
    }
    __syncthreads();
    if (tid < N_) ncount[tid] = lcnt[tid];
  } else if (bid <= 6){                // gh = bhh + Whh @ rnn_state
    #pragma unroll
    for (int p = 0; p < 8; ++p){
      const int rg = (bid-1)*1024 + p*128 + (tid >> 3);   // 0..6143
      const int a  = rg/384, r = rg - a*384;
      const int kk = (tid & 7)*16;
      const float4* w4 = (const float4*)&Whh[r*D_ + kk];
      const float4* x4 = (const float4*)&hs[a*D_ + kk];
      float acc = 0.f;
      #pragma unroll
      for (int q = 0; q < 4; ++q){
        float4 w = w4[q], x = x4[q];
        acc += w.x*x.x + w.y*x.y + w.z*x.z + w.w*x.w;
      }
      acc += __shfl_xor(acc,1); acc += __shfl_xor(acc,2); acc += __shfl_xor(acc,4);
      if ((tid & 7) == 0) ghb[a*384 + r] = acc + bhh[r];
    }
  } else {                             // agent flags: block handles agent bid-7
    const int a = bid - 7;
    if (tid < N_ && nf[(size_t)(a*N_ + tid)*F_] == 1.0f) agent_node[a] = tid;
  }
}

union SMem {
  float feat[4][MAXS*F_];                  // producers: 12.5 KB
  struct {                                 // tails: ~33 KB
    float hsl2[MAXS + 1][DP];
    float xr2s[D_], afl[D_], hsrow[D_], nh[D_];
    float ghl[3*D_], gbuf[3*D_];
    float scores[64];
    int   nsS;
  } t;
};

// ---- D2: 196 attn1 producer blocks + 16 tail blocks, per-agent handoff ---
__global__ void __launch_bounds__(256) k_go(
    const float* __restrict__ nf, const float* __restrict__ hs,
    const int* __restrict__ am,
    const float* __restrict__ Wl1, const float* __restrict__ Wr1,
    const float* __restrict__ att1, const float* __restrict__ b1,
    const float* __restrict__ lnw, const float* __restrict__ lnb,
    const float* __restrict__ Wl2, const float* __restrict__ Wr2,
    const float* __restrict__ att2, const float* __restrict__ b2,
    const float* __restrict__ Wih, const float* __restrict__ bih,
    const float* __restrict__ Wa, const float* __restrict__ ba,
    const float* __restrict__ Wv, const float* __restrict__ bv,
    const int* __restrict__ ncount, const int* __restrict__ nbrs,
    const int* __restrict__ agent_node, const float* __restrict__ ghb,
    float* __restrict__ h_c, int* __restrict__ flags,
    float* __restrict__ out)
{
  const int bid  = blockIdx.x;
  const int tid  = threadIdx.x;
  const int lane = tid & 63;
  const int wv   = tid >> 6;
  __shared__ SMem sm;

  if (bid < NBP){
    // ================= producer: layer-1 GATv2 (R7 body) ===================
    const int wid = bid*4 + wv;                 // 0..783
    const int a = wid / MAXS;
    const int i = wid - a*MAXS;
    const int d_a  = agent_node[a];
    const int dega = min(ncount[d_a], CAP_);
    if (i > dega) return;
    const int v   = (i == 0) ? d_a : nbrs[d_a*CAP_ + (i-1)];
    const int deg = min(ncount[v], CAP_);
    const int c0  = lane*2;

    float* fb = sm.feat[wv];
    int nid = (lane < deg) ? nbrs[v*CAP_ + lane] : 0;
    for (int t = lane; t < (deg+1)*4; t += 64){  // rows: 0=self, 1..deg
      int j = t >> 2, q = (t & 3)*4;
      int s = (j == 0) ? v : __shfl(nid, j-1);
      *(float4*)&fb[j*F_ + q] = *(const float4*)&nf[((size_t)a*N_ + s)*F_ + q];
    }
    asm volatile("s_waitcnt lgkmcnt(0)" ::: "memory");

    float wl0[F_], wl1c[F_];
    #pragma unroll
    for (int k = 0; k < F_; ++k){
      float2 w = *(const float2*)&Wl1[k*D_ + c0];
      wl0[k] = w.x; wl1c[k] = w.y;
    }
    float xr0 = 0.f, xr1 = 0.f;
    #pragma unroll
    for (int k = 0; k < F_; ++k){
      float2 w = *(const float2*)&Wr1[k*D_ + c0];
      float xv = fb[k];
      xr0 += xv*w.x; xr1 += xv*w.y;
    }
    const int head = lane >> 4;
    const float at0 = att1[head*32 + (c0 & 31)];
    const float at1 = att1[head*32 + ((c0+1) & 31)];

    float m = -INFINITY, ls = 0.f, ac0 = 0.f, ac1 = 0.f;
    for (int j = 0; j <= deg; ++j){
      const float* fr = &fb[j*F_];
      float xl0 = 0.f, xl1 = 0.f;
      #pragma unroll
      for (int k = 0; k < F_; k += 4){
        float4 xv = *(const float4*)&fr[k];
        xl0 += xv.x*wl0[k]  + xv.y*wl0[k+1]  + xv.z*wl0[k+2]  + xv.w*wl0[k+3];
        xl1 += xv.x*wl1c[k] + xv.y*wl1c[k+1] + xv.z*wl1c[k+2] + xv.w*wl1c[k+3];
      }
      float t = lrelu(xl0 + xr0)*at0 + lrelu(xl1 + xr1)*at1;
      t += __shfl_xor(t,1); t += __shfl_xor(t,2);
      t += __shfl_xor(t,4); t += __shfl_xor(t,8);      // 16-lane head groups
      float mn = fmaxf(m, t);
      float sc = expf(m - mn), p = expf(t - mn);
      ls = ls*sc + p; ac0 = ac0*sc + p*xl0; ac1 = ac1*sc + p*xl1;
      m = mn;
    }
    float inv = 1.0f/ls;
    float v0 = ac0*inv + b1[c0], v1 = ac1*inv + b1[c0+1];
    float ss = v0 + v1;
    ss += __shfl_xor(ss,1); ss += __shfl_xor(ss,2); ss += __shfl_xor(ss,4);
    ss += __shfl_xor(ss,8); ss += __shfl_xor(ss,16); ss += __shfl_xor(ss,32);
    float mu = ss*(1.0f/D_);
    float d0 = v0 - mu, d1 = v1 - mu;
    float vs = d0*d0 + d1*d1;
    vs += __shfl_xor(vs,1); vs += __shfl_xor(vs,2); vs += __shfl_xor(vs,4);
    vs += __shfl_xor(vs,8); vs += __shfl_xor(vs,16); vs += __shfl_xor(vs,32);
    float rinv = rsqrtf(vs*(1.0f/D_) + 1e-5f);
    float h0 = fmaxf(d0*rinv*lnw[c0]   + lnb[c0],   0.0f);
    float h1 = fmaxf(d1*rinv*lnw[c0+1] + lnb[c0+1], 0.0f);
    *(float2*)&h_c[((size_t)a*MAXS + i)*D_ + c0] = make_float2(h0, h1);
    // per-wave release: vmcnt drain + L2 wb covered by the release atomic
    if (lane == 0)
      __hip_atomic_fetch_add(&flags[a], 1, __ATOMIC_RELEASE, __HIP_MEMORY_SCOPE_AGENT);
    return;
  }

  // ================= tail block: one per agent =============================
  const int a = bid - NBP;

  // overlap with producers: stage rnn_state + gh
  if (tid < D_) sm.t.hsrow[tid] = hs[a*D_ + tid];
  for (int t = tid; t < 3*D_; t += 256) sm.t.ghl[t] = ghb[a*384 + t];

  if (tid == 0){
    int d_a = agent_node[a];
    int nsv = min(ncount[d_a], CAP_) + 1;
    sm.t.nsS = nsv;
    while (__hip_atomic_load(&flags[a], __ATOMIC_ACQUIRE, __HIP_MEMORY_SCOPE_AGENT) < nsv)
      __builtin_amdgcn_s_sleep(2);
  }
  __syncthreads();
  const int ns = sm.t.nsS;

  // T0: stage h rows (padded LDS rows)
  for (int t = tid; t < ns*(D_/4); t += 256){
    int j = t >> 5, q = t & 31;
    ((float4*)sm.t.hsl2[j])[q] = ((const float4*)&h_c[((size_t)a*MAXS + j)*D_])[q];
  }
  __syncthreads();

  // T1: xl2 (+ xr2) — 16-lane groups, each time-shares 4 slot-jobs
  {
    const int l16 = tid & 15, grp = tid >> 4;
    const int c8  = l16*8;
    const bool hasXr = (grp == (ns & 15)) && ((ns >> 4) < 4);
    float4 a0q[4], a1q[4], xa0 = make_float4(0,0,0,0), xa1 = make_float4(0,0,0,0);
    #pragma unroll
    for (int q = 0; q < 4; ++q){ a0q[q] = make_float4(0,0,0,0); a1q[q] = make_float4(0,0,0,0); }
    for (int k = 0; k < D_; ++k){
      float4 w0 = *(const float4*)&Wl2[k*D_ + c8];
      float4 w1 = *(const float4*)&Wl2[k*D_ + c8 + 4];
      #pragma unroll
      for (int q = 0; q < 4; ++q){
        const int j = grp + q*16;
        if (j < ns){
          const float hk = sm.t.hsl2[j][k];
          a0q[q].x += hk*w0.x; a0q[q].y += hk*w0.y; a0q[q].z += hk*w0.z; a0q[q].w += hk*w0.w;
          a1q[q].x += hk*w1.x; a1q[q].y += hk*w1.y; a1q[q].z += hk*w1.z; a1q[q].w += hk*w1.w;
        }
      }
      if (hasXr){
        float4 r0 = *(const float4*)&Wr2[k*D_ + c8];
        float4 r1 = *(const float4*)&Wr2[k*D_ + c8 + 4];
        const float hk = sm.t.hsl2[0][k];
        xa0.x += hk*r0.x; xa0.y += hk*r0.y; xa0.z += hk*r0.z; xa0.w += hk*r0.w;
        xa1.x += hk*r1.x; xa1.y += hk*r1.y; xa1.z += hk*r1.z; xa1.w += hk*r1.w;
      }
    }
    __syncthreads();                       // all reads done before overwrite
    #pragma unroll
    for (int q = 0; q < 4; ++q){
      const int j = grp + q*16;
      if (j < ns){
        *(float4*)&sm.t.hsl2[j][c8]     = a0q[q];
        *(float4*)&sm.t.hsl2[j][c8 + 4] = a1q[q];
      }
    }
    if (hasXr){
      *(float4*)&sm.t.xr2s[c8]     = xa0;
      *(float4*)&sm.t.xr2s[c8 + 4] = xa1;
    }
  }
  __syncthreads();

  // T2a: attention scores (4 waves, 13 rounds)
  {
    const int c0 = lane*2;
    const float xr0 = sm.t.xr2s[c0], xr1 = sm.t.xr2s[c0+1];
    const float at0 = att2[c0], at1 = att2[c0+1];
    for (int q = 0; q < 13; ++q){
      const int s = wv + q*4;
      if (s < ns){
        float2 xl = *(const float2*)&sm.t.hsl2[s][c0];
        float t = lrelu(xl.x + xr0)*at0 + lrelu(xl.y + xr1)*at1;
        t += __shfl_xor(t,1);  t += __shfl_xor(t,2);  t += __shfl_xor(t,4);
        t += __shfl_xor(t,8);  t += __shfl_xor(t,16); t += __shfl_xor(t,32);
        if (lane == 0) sm.t.scores[s] = t;
      }
    }
  }
  __syncthreads();
  // T2b: softmax over ns scores (wave 0)
  if (wv == 0){
    float sc = (lane < ns) ? sm.t.scores[lane] : -INFINITY;
    float m = sc;
    m = fmaxf(m, __shfl_xor(m,1));  m = fmaxf(m, __shfl_xor(m,2));
    m = fmaxf(m, __shfl_xor(m,4));  m = fmaxf(m, __shfl_xor(m,8));
    m = fmaxf(m, __shfl_xor(m,16)); m = fmaxf(m, __shfl_xor(m,32));
    float p = (lane < ns) ? expf(sc - m) : 0.f;
    float s = p;
    s += __shfl_xor(s,1);  s += __shfl_xor(s,2);  s += __shfl_xor(s,4);
    s += __shfl_xor(s,8);  s += __shfl_xor(s,16); s += __shfl_xor(s,32);
    if (lane < ns) sm.t.scores[lane] = p/s;      // alpha
  }
  __syncthreads();
  // T2c: weighted sum -> afl
  if (tid < D_){
    float acc = 0.f;
    for (int i = 0; i < ns; ++i) acc += sm.t.scores[i]*sm.t.hsl2[i][tid];
    sm.t.afl[tid] = acc + b2[tid];
  }
  __syncthreads();

  // T3: gi = bih + Wih @ afl (12 passes, 8 lanes/row, coalesced)
  #pragma unroll
  for (int p = 0; p < 12; ++p){
    const int r  = p*32 + (tid >> 3);
    const int kk = (tid & 7)*16;
    const float4* w4 = (const float4*)&Wih[r*D_ + kk];
    float acc = 0.f;
    #pragma unroll
    for (int q = 0; q < 4; ++q){
      float4 w = w4[q];
      float4 x = *(const float4*)&sm.t.afl[kk + q*4];
      acc += w.x*x.x + w.y*x.y + w.z*x.z + w.w*x.w;
    }
    acc += __shfl_xor(acc,1); acc += __shfl_xor(acc,2); acc += __shfl_xor(acc,4);
    if ((tid & 7) == 0) sm.t.gbuf[r] = acc + bih[r];
  }
  __syncthreads();

  // T4: GRU elementwise
  if (tid < D_){
    float r = sigm(sm.t.gbuf[tid]         + sm.t.ghl[tid]);
    float z = sigm(sm.t.gbuf[D_ + tid]    + sm.t.ghl[D_ + tid]);
    float n = tanhf(sm.t.gbuf[2*D_ + tid] + r*sm.t.ghl[2*D_ + tid]);
    float nv = (1.0f - z)*n + z*sm.t.hsrow[tid];
    sm.t.nh[tid] = nv;
    out[272 + a*D_ + tid] = nv;                  // next_h
  }
  __syncthreads();

  // T5: heads, wave-parallel
  if (wv == 0){
    const int j = lane & 15, q = lane >> 4;
    float acc = 0.f;
    #pragma unroll 8
    for (int k = q*32; k < q*32 + 32; ++k) acc += sm.t.nh[k]*Wa[k*16 + j];
    acc += __shfl_xor(acc,16); acc += __shfl_xor(acc,32);
    if (lane < 16){
      float lg = acc + ba[j];
      if (am[a*16 + j] == 0) lg = -1e8f;
      out[a*16 + j] = lg;                        // logits
    }
  } else if (wv == 1){
    const int c0 = lane*2;
    float acc = sm.t.nh[c0]*Wv[c0] + sm.t.nh[c0+1]*Wv[c0+1];
    acc += __shfl_xor(acc,1);  acc += __shfl_xor(acc,2);  acc += __shfl_xor(acc,4);
    acc += __shfl_xor(acc,8);  acc += __shfl_xor(acc,16); acc += __shfl_xor(acc,32);
    if (lane == 0) out[256 + a] = acc + bv[0];   // values
  }
}

// ---------------------------------------------------------------------------
extern "C" void kernel_launch(void* const* d_in, const int* in_sizes, int n_in,
                              void* d_out, int out_size, void* d_ws, size_t ws_size,
                              hipStream_t stream){
  const float* nf   = (const float*)d_in[0];
  const int*   ei   = (const int*)  d_in[1];
  const float* hs   = (const float*)d_in[2];
  const int*   am   = (const int*)  d_in[3];
  const float* Wl1  = (const float*)d_in[4];
  const float* Wr1  = (const float*)d_in[5];
  const float* att1 = (const float*)d_in[6];
  const float* b1   = (const float*)d_in[7];
  const float* lnw  = (const float*)d_in[8];
  const float* lnb  = (const float*)d_in[9];
  const float* Wl2  = (const float*)d_in[10];
  const float* Wr2  = (const float*)d_in[11];
  const float* att2 = (const float*)d_in[12];
  const float* b2   = (const float*)d_in[13];
  const float* Wih  = (const float*)d_in[14];
  const float* Whh  = (const float*)d_in[15];
  const float* bih  = (const float*)d_in[16];
  const float* bhh  = (const float*)d_in[17];
  const float* Wa   = (const float*)d_in[18];
  const float* ba   = (const float*)d_in[19];
  const float* Wv   = (const float*)d_in[20];
  const float* bv   = (const float*)d_in[21];
  float* out = (float*)d_out;

  int* wsI = (int*)d_ws;
  int*   ncount     = wsI;                      // 1000 ints
  int*   flags      = wsI + 1000;               // 16 ints
  int*   agent_node = wsI + 1024;               // 16 ints
  int*   nbrs       = wsI + 1040;               // 48000 ints (ends 49040)
  float* h_c        = (float*)(wsI + 49040);    // 100352 floats (16B aligned)
  float* ghb        = (float*)(wsI + 149408);   // 6144 floats (16B aligned)

  k_pre<<<23, 1024, 0, stream>>>(ei, nf, hs, Whh, bhh,
                                 ncount, nbrs, agent_node, ghb, flags);
  k_go <<<NBP + NBT, 256, 0, stream>>>(nf, hs, am,
                                       Wl1, Wr1, att1, b1, lnw, lnb,
                                       Wl2, Wr2, att2, b2, Wih, bih,
                                       Wa, ba, Wv, bv,
                                       ncount, nbrs, agent_node, ghb,
                                       h_c, flags, out);
}

// Round 14
// 44.334 us; speedup vs baseline: 2.0542x; 2.0542x over previous
//
#include <hip/hip_runtime.h>
#include <math.h>

#define A_    16
#define N_    1000
#define F_    16
#define E_    16000
#define D_    128
#define SEG_  8           // scan segments (one block each, private LDS histogram)
#define EPB   2000        // edges per scan block: 8*2000 = 16000
#define CAPS  16          // per-(node,segment) capacity (mean 2, 16 = ~9 sigma)
#define CAP_  48          // total in-degree cap (Binomial mean 16, 8 sigma)
#define MAXS  49          // slot 0 = self, 1..48 = in-edges of agent node
#define NB_A1 196         // attn1 blocks: 784 waves = 16*49

__device__ __forceinline__ float lrelu(float v){ return v > 0.0f ? v : 0.2f*v; }
__device__ __forceinline__ float sigm(float x){ return 1.0f/(1.0f + expf(-x)); }

__device__ __forceinline__ int seg_total(const int* __restrict__ ncnt, int v){
  int t = 0;
  #pragma unroll
  for (int s = 0; s < SEG_; ++s) t += ncnt[v*SEG_ + s];
  return t;
}
// ordinal j (0-based) among v's in-edges -> source node id
__device__ __forceinline__ int seg_lookup(const int* __restrict__ ncnt,
                                          const int* __restrict__ nbrs, int v, int j){
  int base = 0, r = 0;
  bool done = false;
  #pragma unroll
  for (int s = 0; s < SEG_; ++s){
    int c = ncnt[v*SEG_ + s];
    if (!done && j < base + c){ r = nbrs[(v*SEG_ + s)*CAPS + (j - base)]; done = true; }
    base += c;
  }
  return r;
}

// ---- D1: blocks 0-7 segmented scan | 8-31 gh GEMV | 32-47 agent flags ----
__global__ void __launch_bounds__(256) k_pre(
    const int* __restrict__ ei, const float* __restrict__ nf,
    const float* __restrict__ hs, const float* __restrict__ Whh,
    const float* __restrict__ bhh,
    int* __restrict__ ncnt, int* __restrict__ nbrs,
    int* __restrict__ agent_node, float* __restrict__ ghb){
  const int bid = blockIdx.x, tid = threadIdx.x;

  if (bid < SEG_){                     // private-LDS histogram over own slice
    __shared__ int lcnt[N_];
    for (int t = tid; t < N_; t += 256) lcnt[t] = 0;
    __syncthreads();
    const int base = bid*EPB;
    #pragma unroll
    for (int r = 0; r < 8; ++r){
      const int e = base + r*256 + tid;
      if (e < base + EPB && e < E_){
        int src = ei[e], dst = ei[E_ + e];
        int pos = atomicAdd(&lcnt[dst], 1);
        if (pos < CAPS) nbrs[(dst*SEG_ + bid)*CAPS + pos] = src;
      }
    }
    __syncthreads();
    for (int t = tid; t < N_; t += 256) ncnt[t*SEG_ + bid] = min(lcnt[t], CAPS);
  } else if (bid < SEG_ + 24){         // gh = bhh + Whh @ rnn_state (256 rows/blk)
    const int rg = (bid - SEG_)*256 + tid;       // 0..6143
    const int a = rg/384, r = rg - a*384;
    const float4* w4 = (const float4*)&Whh[r*D_];
    const float4* x4 = (const float4*)&hs[a*D_];
    float acc = bhh[r];
    #pragma unroll
    for (int k = 0; k < D_/4; ++k){
      float4 w = w4[k], x = x4[k];
      acc += w.x*x.x + w.y*x.y + w.z*x.z + w.w*x.w;
    }
    ghb[a*384 + r] = acc;
  } else {                             // agent flag scan
    const int a = bid - SEG_ - 24;
    for (int t = tid; t < N_; t += 256)
      if (nf[(size_t)(a*N_ + t)*F_] == 1.0f) agent_node[a] = t;
  }
}

// ---- D2: layer-1 GATv2 (4x32) + LN + ReLU, wave per (agent,slot) ---------
__global__ void __launch_bounds__(256) k_attn1(
    const float* __restrict__ nf, const int* __restrict__ agent_node,
    const int* __restrict__ ncnt, const int* __restrict__ nbrs,
    const float* __restrict__ Wl1, const float* __restrict__ Wr1,
    const float* __restrict__ att1, const float* __restrict__ b1,
    const float* __restrict__ lnw, const float* __restrict__ lnb,
    float* __restrict__ h_c){
  const int tid  = threadIdx.x;
  const int lane = tid & 63;
  const int wv   = tid >> 6;
  const int wid  = blockIdx.x*4 + wv;
  const int a = wid / MAXS;
  const int i = wid - a*MAXS;
  const int d_a  = agent_node[a];
  const int dega = min(seg_total(ncnt, d_a), CAP_);
  if (i > dega) return;
  const int v   = (i == 0) ? d_a : seg_lookup(ncnt, nbrs, d_a, i-1);
  const int deg = min(seg_total(ncnt, v), CAP_);
  const int c0  = lane*2;

  __shared__ float feat[4][MAXS*F_];
  float* fb = feat[wv];

  int nid = (lane < deg) ? seg_lookup(ncnt, nbrs, v, lane) : 0;
  for (int t = lane; t < (deg+1)*4; t += 64){     // rows: 0=self, 1..deg
    int j = t >> 2, q = (t & 3)*4;
    int s = (j == 0) ? v : __shfl(nid, j-1);
    *(float4*)&fb[j*F_ + q] = *(const float4*)&nf[((size_t)a*N_ + s)*F_ + q];
  }
  asm volatile("s_waitcnt lgkmcnt(0)" ::: "memory");

  float wl0[F_], wl1c[F_];
  #pragma unroll
  for (int k = 0; k < F_; ++k){
    float2 w = *(const float2*)&Wl1[k*D_ + c0];
    wl0[k] = w.x; wl1c[k] = w.y;
  }
  float xr0 = 0.f, xr1 = 0.f;
  #pragma unroll
  for (int k = 0; k < F_; ++k){
    float2 w = *(const float2*)&Wr1[k*D_ + c0];
    float xv = fb[k];
    xr0 += xv*w.x; xr1 += xv*w.y;
  }
  const int head = lane >> 4;
  const float at0 = att1[head*32 + (c0 & 31)];
  const float at1 = att1[head*32 + ((c0+1) & 31)];

  float m = -INFINITY, ls = 0.f, ac0 = 0.f, ac1 = 0.f;
  for (int j = 0; j <= deg; ++j){
    const float* fr = &fb[j*F_];
    float xl0 = 0.f, xl1 = 0.f;
    #pragma unroll
    for (int k = 0; k < F_; k += 4){
      float4 xv = *(const float4*)&fr[k];
      xl0 += xv.x*wl0[k]  + xv.y*wl0[k+1]  + xv.z*wl0[k+2]  + xv.w*wl0[k+3];
      xl1 += xv.x*wl1c[k] + xv.y*wl1c[k+1] + xv.z*wl1c[k+2] + xv.w*wl1c[k+3];
    }
    float t = lrelu(xl0 + xr0)*at0 + lrelu(xl1 + xr1)*at1;
    t += __shfl_xor(t,1); t += __shfl_xor(t,2);
    t += __shfl_xor(t,4); t += __shfl_xor(t,8);         // 16-lane head groups
    float mn = fmaxf(m, t);
    float sc = expf(m - mn), p = expf(t - mn);
    ls = ls*sc + p; ac0 = ac0*sc + p*xl0; ac1 = ac1*sc + p*xl1;
    m = mn;
  }
  float inv = 1.0f/ls;
  float v0 = ac0*inv + b1[c0], v1 = ac1*inv + b1[c0+1];
  float ss = v0 + v1;
  ss += __shfl_xor(ss,1); ss += __shfl_xor(ss,2); ss += __shfl_xor(ss,4);
  ss += __shfl_xor(ss,8); ss += __shfl_xor(ss,16); ss += __shfl_xor(ss,32);
  float mu = ss*(1.0f/D_);
  float d0 = v0 - mu, d1 = v1 - mu;
  float vs = d0*d0 + d1*d1;
  vs += __shfl_xor(vs,1); vs += __shfl_xor(vs,2); vs += __shfl_xor(vs,4);
  vs += __shfl_xor(vs,8); vs += __shfl_xor(vs,16); vs += __shfl_xor(vs,32);
  float rinv = rsqrtf(vs*(1.0f/D_) + 1e-5f);
  float h0 = fmaxf(d0*rinv*lnw[c0]   + lnb[c0],   0.0f);
  float h1 = fmaxf(d1*rinv*lnw[c0+1] + lnb[c0+1], 0.0f);
  *(float2*)&h_c[((size_t)a*MAXS + i)*D_ + c0] = make_float2(h0, h1);
}

// ---- D3: per-agent tail: gemm2 + attn2 + gi + GRU + heads ----------------
__global__ void __launch_bounds__(1024) k_tail(
    const float* __restrict__ h_c, const float* __restrict__ ghb,
    const int* __restrict__ agent_node, const int* __restrict__ ncnt,
    const float* __restrict__ hs, const int* __restrict__ am,
    const float* __restrict__ Wl2, const float* __restrict__ Wr2,
    const float* __restrict__ att2, const float* __restrict__ b2,
    const float* __restrict__ Wih, const float* __restrict__ bih,
    const float* __restrict__ Wa, const float* __restrict__ ba,
    const float* __restrict__ Wv, const float* __restrict__ bv,
    float* __restrict__ out){
  const int a    = blockIdx.x;
  const int tid  = threadIdx.x;
  const int lane = tid & 63;
  const int wv   = tid >> 6;

  __shared__ float hsl2[MAXS][D_];     // h1 rows, overwritten in-place by xl2
  __shared__ float xr2s[D_], afl[D_], ghl[3*D_], gbuf[3*D_], hsrow[D_], nh[D_];
  __shared__ float scores[64];

  const int d_a = agent_node[a];
  const int ns  = min(seg_total(ncnt, d_a), CAP_) + 1;

  // T0: stage h rows + gh + rnn_state
  for (int t = tid; t < ns*(D_/4); t += 1024){
    int j = t >> 5, q = t & 31;
    ((float4*)hsl2[j])[q] = ((const float4*)&h_c[((size_t)a*MAXS + j)*D_])[q];
  }
  if (tid < D_) hsrow[tid] = hs[a*D_ + tid];
  if (tid >= D_ && tid < D_ + 3*D_) ghl[tid - D_] = ghb[a*384 + (tid - D_)];
  __syncthreads();

  // T1: xl2 for all slots + xr2; 64 jobs x 16 lanes, coalesced float4 loads
  {
    const int j  = tid >> 4;
    const int c8 = (tid & 15)*8;
    float4 acc0 = make_float4(0,0,0,0), acc1 = make_float4(0,0,0,0);
    if (j <= ns){
      const float* W  = (j == ns) ? Wr2 : Wl2;
      const float* hR = (j == ns) ? hsl2[0] : hsl2[j];
      #pragma unroll 4
      for (int k = 0; k < D_; ++k){
        const float hk = hR[k];
        float4 w0 = *(const float4*)&W[k*D_ + c8];
        float4 w1 = *(const float4*)&W[k*D_ + c8 + 4];
        acc0.x += hk*w0.x; acc0.y += hk*w0.y; acc0.z += hk*w0.z; acc0.w += hk*w0.w;
        acc1.x += hk*w1.x; acc1.y += hk*w1.y; acc1.z += hk*w1.z; acc1.w += hk*w1.w;
      }
    }
    __syncthreads();                       // all reads done before overwrite
    if (j < ns){
      *(float4*)&hsl2[j][c8]     = acc0;
      *(float4*)&hsl2[j][c8 + 4] = acc1;
    } else if (j == ns){
      *(float4*)&xr2s[c8]     = acc0;
      *(float4*)&xr2s[c8 + 4] = acc1;
    }
  }
  __syncthreads();

  // T2a: attention scores, wave w handles slots w, w+16, w+32, w+48
  {
    const int c0 = lane*2;
    const float xr0 = xr2s[c0], xr1 = xr2s[c0+1];
    const float at0 = att2[c0], at1 = att2[c0+1];
    for (int q = 0; q < 4; ++q){
      const int s = wv + q*16;
      if (s < ns){
        float2 xl = *(const float2*)&hsl2[s][c0];
        float t = lrelu(xl.x + xr0)*at0 + lrelu(xl.y + xr1)*at1;
        t += __shfl_xor(t,1);  t += __shfl_xor(t,2);  t += __shfl_xor(t,4);
        t += __shfl_xor(t,8);  t += __shfl_xor(t,16); t += __shfl_xor(t,32);
        if (lane == 0) scores[s] = t;
      }
    }
  }
  __syncthreads();
  // T2b: softmax over ns scores (wave 0, lane-parallel)
  if (wv == 0){
    float sc = (lane < ns) ? scores[lane] : -INFINITY;
    float m = sc;
    m = fmaxf(m, __shfl_xor(m,1));  m = fmaxf(m, __shfl_xor(m,2));
    m = fmaxf(m, __shfl_xor(m,4));  m = fmaxf(m, __shfl_xor(m,8));
    m = fmaxf(m, __shfl_xor(m,16)); m = fmaxf(m, __shfl_xor(m,32));
    float p = (lane < ns) ? expf(sc - m) : 0.f;
    float s = p;
    s += __shfl_xor(s,1);  s += __shfl_xor(s,2);  s += __shfl_xor(s,4);
    s += __shfl_xor(s,8);  s += __shfl_xor(s,16); s += __shfl_xor(s,32);
    if (lane < ns) scores[lane] = p/s;           // alpha
  }
  __syncthreads();
  // T2c: weighted sum -> afl
  if (tid < D_){
    float acc = 0.f;
    for (int i = 0; i < ns; ++i) acc += scores[i]*hsl2[i][tid];
    afl[tid] = acc + b2[tid];
  }
  __syncthreads();

  // T3: gi = bih + Wih @ afl — 8 lanes per row, coalesced float4 reads
  #pragma unroll
  for (int p = 0; p < 3; ++p){
    const int r  = p*128 + (tid >> 3);
    const int kk = (tid & 7)*16;
    const float4* w4 = (const float4*)&Wih[r*D_ + kk];
    float acc = 0.f;
    #pragma unroll
    for (int q = 0; q < 4; ++q){
      float4 w = w4[q];
      float4 x = *(const float4*)&afl[kk + q*4];
      acc += w.x*x.x + w.y*x.y + w.z*x.z + w.w*x.w;
    }
    acc += __shfl_xor(acc,1); acc += __shfl_xor(acc,2); acc += __shfl_xor(acc,4);
    if ((tid & 7) == 0) gbuf[r] = acc + bih[r];
  }
  __syncthreads();

  // T4: GRU elementwise
  if (tid < D_){
    float r = sigm(gbuf[tid]         + ghl[tid]);
    float z = sigm(gbuf[D_ + tid]    + ghl[D_ + tid]);
    float n = tanhf(gbuf[2*D_ + tid] + r*ghl[2*D_ + tid]);
    float nv = (1.0f - z)*n + z*hsrow[tid];
    nh[tid] = nv;
    out[272 + a*D_ + tid] = nv;                  // next_h
  }
  __syncthreads();

  // T5: heads, wave-parallel
  if (wv == 0){
    const int j = lane & 15, q = lane >> 4;      // action j, k-quarter q
    float acc = 0.f;
    #pragma unroll 8
    for (int k = q*32; k < q*32 + 32; ++k) acc += nh[k]*Wa[k*16 + j];
    acc += __shfl_xor(acc,16); acc += __shfl_xor(acc,32);
    if (lane < 16){
      float lg = acc + ba[j];
      if (am[a*16 + j] == 0) lg = -1e8f;
      out[a*16 + j] = lg;                        // logits
    }
  } else if (wv == 1){
    const int c0 = lane*2;
    float acc = nh[c0]*Wv[c0] + nh[c0+1]*Wv[c0+1];
    acc += __shfl_xor(acc,1);  acc += __shfl_xor(acc,2);  acc += __shfl_xor(acc,4);
    acc += __shfl_xor(acc,8);  acc += __shfl_xor(acc,16); acc += __shfl_xor(acc,32);
    if (lane == 0) out[256 + a] = acc + bv[0];   // values
  }
}

// ---------------------------------------------------------------------------
extern "C" void kernel_launch(void* const* d_in, const int* in_sizes, int n_in,
                              void* d_out, int out_size, void* d_ws, size_t ws_size,
                              hipStream_t stream){
  const float* nf   = (const float*)d_in[0];
  const int*   ei   = (const int*)  d_in[1];
  const float* hs   = (const float*)d_in[2];
  const int*   am   = (const int*)  d_in[3];
  const float* Wl1  = (const float*)d_in[4];
  const float* Wr1  = (const float*)d_in[5];
  const float* att1 = (const float*)d_in[6];
  const float* b1   = (const float*)d_in[7];
  const float* lnw  = (const float*)d_in[8];
  const float* lnb  = (const float*)d_in[9];
  const float* Wl2  = (const float*)d_in[10];
  const float* Wr2  = (const float*)d_in[11];
  const float* att2 = (const float*)d_in[12];
  const float* b2   = (const float*)d_in[13];
  const float* Wih  = (const float*)d_in[14];
  const float* Whh  = (const float*)d_in[15];
  const float* bih  = (const float*)d_in[16];
  const float* bhh  = (const float*)d_in[17];
  const float* Wa   = (const float*)d_in[18];
  const float* ba   = (const float*)d_in[19];
  const float* Wv   = (const float*)d_in[20];
  const float* bv   = (const float*)d_in[21];
  float* out = (float*)d_out;

  int* wsI = (int*)d_ws;
  int*   ncnt       = wsI;                      // [1000][8] ints
  int*   agent_node = wsI + 8000;               // 16 ints
  int*   nbrs       = wsI + 8192;               // [1000][8][16] ints -> ends 136192
  float* h_c        = (float*)(wsI + 136192);   // 16*49*128 floats (16B aligned)
  float* ghb        = (float*)(wsI + 236544);   // 16*384 floats (16B aligned)

  k_pre  <<<SEG_ + 24 + A_, 256, 0, stream>>>(ei, nf, hs, Whh, bhh,
                                              ncnt, nbrs, agent_node, ghb);
  k_attn1<<<NB_A1, 256, 0, stream>>>(nf, agent_node, ncnt, nbrs,
                                     Wl1, Wr1, att1, b1, lnw, lnb, h_c);
  k_tail <<<A_, 1024, 0, stream>>>(h_c, ghb, agent_node, ncnt, hs, am,
                                   Wl2, Wr2, att2, b2, Wih, bih,
                                   Wa, ba, Wv, bv, out);
}

// Round 15
// 33.774 us; speedup vs baseline: 2.6965x; 1.3127x over previous
//
#include <hip/hip_runtime.h>
#include <math.h>

#define A_    16
#define N_    1000
#define F_    16
#define E_    16000
#define D_    128
#define SEG_  8           // scan segments (one block each, private LDS histogram)
#define EPB   2000        // edges per scan block: 8*2000 = 16000
#define CAPS  16          // per-(node,segment) capacity (mean 2, ~9 sigma)
#define CAP_  48          // total in-degree cap (Binomial mean 16, 8 sigma)
#define MAXS  49          // slot 0 = self, 1..48 = in-edges of agent node
#define NB_A1 196         // attn1 blocks: 784 waves = 16*49
#define NB_GH 24          // gh blocks (6144 = 16*384 row-dots)

__device__ __forceinline__ float lrelu(float v){ return v > 0.0f ? v : 0.2f*v; }
__device__ __forceinline__ float sigm(float x){ return 1.0f/(1.0f + expf(-x)); }

__device__ __forceinline__ int seg_total(const int* __restrict__ ncnt, int v){
  int t = 0;
  #pragma unroll
  for (int s = 0; s < SEG_; ++s) t += ncnt[v*SEG_ + s];
  return t;
}
// ordinal j (0-based) among v's in-edges -> source node id
__device__ __forceinline__ int seg_lookup(const int* __restrict__ ncnt,
                                          const int* __restrict__ nbrs, int v, int j){
  int base = 0, r = 0;
  bool done = false;
  #pragma unroll
  for (int s = 0; s < SEG_; ++s){
    int c = ncnt[v*SEG_ + s];
    if (!done && j < base + c){ r = nbrs[(v*SEG_ + s)*CAPS + (j - base)]; done = true; }
    base += c;
  }
  return r;
}

// ---- D1: blocks 0-7 segmented edge scan | blocks 8-23 agent flags --------
__global__ void __launch_bounds__(256) k_pre(
    const int* __restrict__ ei, const float* __restrict__ nf,
    int* __restrict__ ncnt, int* __restrict__ nbrs,
    int* __restrict__ agent_node){
  const int bid = blockIdx.x, tid = threadIdx.x;

  if (bid < SEG_){                     // private-LDS histogram over own slice
    __shared__ int lcnt[N_];
    for (int t = tid; t < N_; t += 256) lcnt[t] = 0;
    __syncthreads();
    const int base = bid*EPB;
    #pragma unroll
    for (int r = 0; r < 8; ++r){
      const int e = base + r*256 + tid;
      if (e < base + EPB && e < E_){
        int src = ei[e], dst = ei[E_ + e];
        int pos = atomicAdd(&lcnt[dst], 1);
        if (pos < CAPS) nbrs[(dst*SEG_ + bid)*CAPS + pos] = src;
      }
    }
    __syncthreads();
    for (int t = tid; t < N_; t += 256) ncnt[t*SEG_ + bid] = min(lcnt[t], CAPS);
  } else {                             // agent flag scan (one block per agent)
    const int a = bid - SEG_;
    for (int t = tid; t < N_; t += 256)
      if (nf[(size_t)(a*N_ + t)*F_] == 1.0f) agent_node[a] = t;
  }
}

// ---- D2: blocks 0-195 = layer-1 GATv2 + LN/ReLU + fused xl2/xr2 GEMV;
//          blocks 196-219 = gh = bhh + Whh @ rnn_state --------------------
__global__ void __launch_bounds__(256) k_mid(
    const float* __restrict__ nf, const int* __restrict__ agent_node,
    const int* __restrict__ ncnt, const int* __restrict__ nbrs,
    const float* __restrict__ Wl1, const float* __restrict__ Wr1,
    const float* __restrict__ att1, const float* __restrict__ b1,
    const float* __restrict__ lnw, const float* __restrict__ lnb,
    const float* __restrict__ Wl2, const float* __restrict__ Wr2,
    const float* __restrict__ hs, const float* __restrict__ Whh,
    const float* __restrict__ bhh,
    float* __restrict__ xl2_c, float* __restrict__ xr2g,
    float* __restrict__ ghb){
  const int tid  = threadIdx.x;

  if (blockIdx.x >= NB_A1){            // ---- gh rows (independent of scan)
    const int rg = (blockIdx.x - NB_A1)*256 + tid;   // 0..6143
    const int a = rg/384, r = rg - a*384;
    const float4* w4 = (const float4*)&Whh[r*D_];
    const float4* x4 = (const float4*)&hs[a*D_];
    float acc = bhh[r];
    #pragma unroll
    for (int k = 0; k < D_/4; ++k){
      float4 w = w4[k], x = x4[k];
      acc += w.x*x.x + w.y*x.y + w.z*x.z + w.w*x.w;
    }
    ghb[a*384 + r] = acc;
    return;
  }

  const int lane = tid & 63;
  const int wv   = tid >> 6;
  const int wid  = blockIdx.x*4 + wv;
  const int a = wid / MAXS;
  const int i = wid - a*MAXS;
  const int d_a  = agent_node[a];
  const int dega = min(seg_total(ncnt, d_a), CAP_);
  if (i > dega) return;
  const int v   = (i == 0) ? d_a : seg_lookup(ncnt, nbrs, d_a, i-1);
  const int deg = min(seg_total(ncnt, v), CAP_);
  const int c0  = lane*2;

  __shared__ float feat[4][MAXS*F_];
  float* fb = feat[wv];

  int nid = (lane < deg) ? seg_lookup(ncnt, nbrs, v, lane) : 0;
  for (int t = lane; t < (deg+1)*4; t += 64){     // rows: 0=self, 1..deg
    int j = t >> 2, q = (t & 3)*4;
    int s = (j == 0) ? v : __shfl(nid, j-1);
    *(float4*)&fb[j*F_ + q] = *(const float4*)&nf[((size_t)a*N_ + s)*F_ + q];
  }
  asm volatile("s_waitcnt lgkmcnt(0)" ::: "memory");

  float wl0[F_], wl1c[F_];
  #pragma unroll
  for (int k = 0; k < F_; ++k){
    float2 w = *(const float2*)&Wl1[k*D_ + c0];
    wl0[k] = w.x; wl1c[k] = w.y;
  }
  float xr0 = 0.f, xr1 = 0.f;
  #pragma unroll
  for (int k = 0; k < F_; ++k){
    float2 w = *(const float2*)&Wr1[k*D_ + c0];
    float xv = fb[k];
    xr0 += xv*w.x; xr1 += xv*w.y;
  }
  const int head = lane >> 4;
  const float at0 = att1[head*32 + (c0 & 31)];
  const float at1 = att1[head*32 + ((c0+1) & 31)];

  float m = -INFINITY, ls = 0.f, ac0 = 0.f, ac1 = 0.f;
  for (int j = 0; j <= deg; ++j){
    const float* fr = &fb[j*F_];
    float xl0 = 0.f, xl1 = 0.f;
    #pragma unroll
    for (int k = 0; k < F_; k += 4){
      float4 xv = *(const float4*)&fr[k];
      xl0 += xv.x*wl0[k]  + xv.y*wl0[k+1]  + xv.z*wl0[k+2]  + xv.w*wl0[k+3];
      xl1 += xv.x*wl1c[k] + xv.y*wl1c[k+1] + xv.z*wl1c[k+2] + xv.w*wl1c[k+3];
    }
    float t = lrelu(xl0 + xr0)*at0 + lrelu(xl1 + xr1)*at1;
    t += __shfl_xor(t,1); t += __shfl_xor(t,2);
    t += __shfl_xor(t,4); t += __shfl_xor(t,8);         // 16-lane head groups
    float mn = fmaxf(m, t);
    float sc = expf(m - mn), p = expf(t - mn);
    ls = ls*sc + p; ac0 = ac0*sc + p*xl0; ac1 = ac1*sc + p*xl1;
    m = mn;
  }
  float inv = 1.0f/ls;
  float v0 = ac0*inv + b1[c0], v1 = ac1*inv + b1[c0+1];
  float ss = v0 + v1;
  ss += __shfl_xor(ss,1); ss += __shfl_xor(ss,2); ss += __shfl_xor(ss,4);
  ss += __shfl_xor(ss,8); ss += __shfl_xor(ss,16); ss += __shfl_xor(ss,32);
  float mu = ss*(1.0f/D_);
  float d0 = v0 - mu, d1 = v1 - mu;
  float vs = d0*d0 + d1*d1;
  vs += __shfl_xor(vs,1); vs += __shfl_xor(vs,2); vs += __shfl_xor(vs,4);
  vs += __shfl_xor(vs,8); vs += __shfl_xor(vs,16); vs += __shfl_xor(vs,32);
  float rinv = rsqrtf(vs*(1.0f/D_) + 1e-5f);
  float h0 = fmaxf(d0*rinv*lnw[c0]   + lnb[c0],   0.0f);
  float h1 = fmaxf(d1*rinv*lnw[c0+1] + lnb[c0+1], 0.0f);

  // ---- fused epilogue: park h row in wave-local LDS, xl2 = h @ Wl2 -------
  fb[c0] = h0; fb[c0+1] = h1;
  asm volatile("s_waitcnt lgkmcnt(0)" ::: "memory");    // wave-coherent LDS

  float xa0 = 0.f, xa1 = 0.f;
  #pragma unroll 8
  for (int k = 0; k < D_; k += 4){
    float4 hv = *(const float4*)&fb[k];
    float2 w0 = *(const float2*)&Wl2[(k+0)*D_ + c0];
    float2 w1 = *(const float2*)&Wl2[(k+1)*D_ + c0];
    float2 w2 = *(const float2*)&Wl2[(k+2)*D_ + c0];
    float2 w3 = *(const float2*)&Wl2[(k+3)*D_ + c0];
    xa0 += hv.x*w0.x + hv.y*w1.x + hv.z*w2.x + hv.w*w3.x;
    xa1 += hv.x*w0.y + hv.y*w1.y + hv.z*w2.y + hv.w*w3.y;
  }
  *(float2*)&xl2_c[((size_t)a*MAXS + i)*D_ + c0] = make_float2(xa0, xa1);

  if (i == 0){                         // agent slot also produces xr2
    float xb0 = 0.f, xb1 = 0.f;
    #pragma unroll 8
    for (int k = 0; k < D_; k += 4){
      float4 hv = *(const float4*)&fb[k];
      float2 w0 = *(const float2*)&Wr2[(k+0)*D_ + c0];
      float2 w1 = *(const float2*)&Wr2[(k+1)*D_ + c0];
      float2 w2 = *(const float2*)&Wr2[(k+2)*D_ + c0];
      float2 w3 = *(const float2*)&Wr2[(k+3)*D_ + c0];
      xb0 += hv.x*w0.x + hv.y*w1.x + hv.z*w2.x + hv.w*w3.x;
      xb1 += hv.x*w0.y + hv.y*w1.y + hv.z*w2.y + hv.w*w3.y;
    }
    *(float2*)&xr2g[a*D_ + c0] = make_float2(xb0, xb1);
  }
}

// ---- D3: per-agent tail: attn2 + gi + GRU + heads (T1 eliminated) --------
__global__ void __launch_bounds__(1024) k_tail(
    const float* __restrict__ xl2_c, const float* __restrict__ xr2g,
    const float* __restrict__ ghb,
    const int* __restrict__ agent_node, const int* __restrict__ ncnt,
    const float* __restrict__ hs, const int* __restrict__ am,
    const float* __restrict__ att2, const float* __restrict__ b2,
    const float* __restrict__ Wih, const float* __restrict__ bih,
    const float* __restrict__ Wa, const float* __restrict__ ba,
    const float* __restrict__ Wv, const float* __restrict__ bv,
    float* __restrict__ out){
  const int a    = blockIdx.x;
  const int tid  = threadIdx.x;
  const int lane = tid & 63;
  const int wv   = tid >> 6;

  __shared__ float xsl[MAXS][D_];      // xl2 rows
  __shared__ float xr2s[D_], afl[D_], ghl[3*D_], gbuf[3*D_], hsrow[D_], nh[D_];
  __shared__ float scores[64];

  const int d_a = agent_node[a];
  const int ns  = min(seg_total(ncnt, d_a), CAP_) + 1;

  // T0: stage xl2 rows + xr2 + gh + rnn_state
  for (int t = tid; t < ns*(D_/4); t += 1024){
    int j = t >> 5, q = t & 31;
    ((float4*)xsl[j])[q] = ((const float4*)&xl2_c[((size_t)a*MAXS + j)*D_])[q];
  }
  if (tid < D_) hsrow[tid] = hs[a*D_ + tid];
  else if (tid < 4*D_) ghl[tid - D_] = ghb[a*384 + (tid - D_)];
  else if (tid < 5*D_) xr2s[tid - 4*D_] = xr2g[a*D_ + (tid - 4*D_)];
  __syncthreads();

  // T2a: attention scores, wave w handles slots w, w+16, w+32, w+48
  {
    const int c0 = lane*2;
    const float xr0 = xr2s[c0], xr1 = xr2s[c0+1];
    const float at0 = att2[c0], at1 = att2[c0+1];
    for (int q = 0; q < 4; ++q){
      const int s = wv + q*16;
      if (s < ns){
        float2 xl = *(const float2*)&xsl[s][c0];
        float t = lrelu(xl.x + xr0)*at0 + lrelu(xl.y + xr1)*at1;
        t += __shfl_xor(t,1);  t += __shfl_xor(t,2);  t += __shfl_xor(t,4);
        t += __shfl_xor(t,8);  t += __shfl_xor(t,16); t += __shfl_xor(t,32);
        if (lane == 0) scores[s] = t;
      }
    }
  }
  __syncthreads();
  // T2b: softmax over ns scores (wave 0, lane-parallel)
  if (wv == 0){
    float sc = (lane < ns) ? scores[lane] : -INFINITY;
    float m = sc;
    m = fmaxf(m, __shfl_xor(m,1));  m = fmaxf(m, __shfl_xor(m,2));
    m = fmaxf(m, __shfl_xor(m,4));  m = fmaxf(m, __shfl_xor(m,8));
    m = fmaxf(m, __shfl_xor(m,16)); m = fmaxf(m, __shfl_xor(m,32));
    float p = (lane < ns) ? expf(sc - m) : 0.f;
    float s = p;
    s += __shfl_xor(s,1);  s += __shfl_xor(s,2);  s += __shfl_xor(s,4);
    s += __shfl_xor(s,8);  s += __shfl_xor(s,16); s += __shfl_xor(s,32);
    if (lane < ns) scores[lane] = p/s;           // alpha
  }
  __syncthreads();
  // T2c: weighted sum -> afl
  if (tid < D_){
    float acc = 0.f;
    for (int i = 0; i < ns; ++i) acc += scores[i]*xsl[i][tid];
    afl[tid] = acc + b2[tid];
  }
  __syncthreads();

  // T3: gi = bih + Wih @ afl — 8 lanes per row, coalesced float4 reads
  #pragma unroll
  for (int p = 0; p < 3; ++p){
    const int r  = p*128 + (tid >> 3);
    const int kk = (tid & 7)*16;
    const float4* w4 = (const float4*)&Wih[r*D_ + kk];
    float acc = 0.f;
    #pragma unroll
    for (int q = 0; q < 4; ++q){
      float4 w = w4[q];
      float4 x = *(const float4*)&afl[kk + q*4];
      acc += w.x*x.x + w.y*x.y + w.z*x.z + w.w*x.w;
    }
    acc += __shfl_xor(acc,1); acc += __shfl_xor(acc,2); acc += __shfl_xor(acc,4);
    if ((tid & 7) == 0) gbuf[r] = acc + bih[r];
  }
  __syncthreads();

  // T4: GRU elementwise
  if (tid < D_){
    float r = sigm(gbuf[tid]         + ghl[tid]);
    float z = sigm(gbuf[D_ + tid]    + ghl[D_ + tid]);
    float n = tanhf(gbuf[2*D_ + tid] + r*ghl[2*D_ + tid]);
    float nv = (1.0f - z)*n + z*hsrow[tid];
    nh[tid] = nv;
    out[272 + a*D_ + tid] = nv;                  // next_h
  }
  __syncthreads();

  // T5: heads, wave-parallel
  if (wv == 0){
    const int j = lane & 15, q = lane >> 4;      // action j, k-quarter q
    float acc = 0.f;
    #pragma unroll 8
    for (int k = q*32; k < q*32 + 32; ++k) acc += nh[k]*Wa[k*16 + j];
    acc += __shfl_xor(acc,16); acc += __shfl_xor(acc,32);
    if (lane < 16){
      float lg = acc + ba[j];
      if (am[a*16 + j] == 0) lg = -1e8f;
      out[a*16 + j] = lg;                        // logits
    }
  } else if (wv == 1){
    const int c0 = lane*2;
    float acc = nh[c0]*Wv[c0] + nh[c0+1]*Wv[c0+1];
    acc += __shfl_xor(acc,1);  acc += __shfl_xor(acc,2);  acc += __shfl_xor(acc,4);
    acc += __shfl_xor(acc,8);  acc += __shfl_xor(acc,16); acc += __shfl_xor(acc,32);
    if (lane == 0) out[256 + a] = acc + bv[0];   // values
  }
}

// ---------------------------------------------------------------------------
extern "C" void kernel_launch(void* const* d_in, const int* in_sizes, int n_in,
                              void* d_out, int out_size, void* d_ws, size_t ws_size,
                              hipStream_t stream){
  const float* nf   = (const float*)d_in[0];
  const int*   ei   = (const int*)  d_in[1];
  const float* hs   = (const float*)d_in[2];
  const int*   am   = (const int*)  d_in[3];
  const float* Wl1  = (const float*)d_in[4];
  const float* Wr1  = (const float*)d_in[5];
  const float* att1 = (const float*)d_in[6];
  const float* b1   = (const float*)d_in[7];
  const float* lnw  = (const float*)d_in[8];
  const float* lnb  = (const float*)d_in[9];
  const float* Wl2  = (const float*)d_in[10];
  const float* Wr2  = (const float*)d_in[11];
  const float* att2 = (const float*)d_in[12];
  const float* b2   = (const float*)d_in[13];
  const float* Wih  = (const float*)d_in[14];
  const float* Whh  = (const float*)d_in[15];
  const float* bih  = (const float*)d_in[16];
  const float* bhh  = (const float*)d_in[17];
  const float* Wa   = (const float*)d_in[18];
  const float* ba   = (const float*)d_in[19];
  const float* Wv   = (const float*)d_in[20];
  const float* bv   = (const float*)d_in[21];
  float* out = (float*)d_out;

  int* wsI = (int*)d_ws;
  int*   ncnt       = wsI;                      // [1000][8] ints
  int*   agent_node = wsI + 8000;               // 16 ints (pad to 8192)
  int*   nbrs       = wsI + 8192;               // [1000][8][16] ints -> ends 136192
  float* xl2_c      = (float*)(wsI + 136192);   // 16*49*128 floats -> ends 236544
  float* xr2g       = (float*)(wsI + 236544);   // 16*128 floats -> ends 238592
  float* ghb        = (float*)(wsI + 238592);   // 16*384 floats -> ends 244736

  k_pre <<<SEG_ + A_, 256, 0, stream>>>(ei, nf, ncnt, nbrs, agent_node);
  k_mid <<<NB_A1 + NB_GH, 256, 0, stream>>>(nf, agent_node, ncnt, nbrs,
                                            Wl1, Wr1, att1, b1, lnw, lnb,
                                            Wl2, Wr2, hs, Whh, bhh,
                                            xl2_c, xr2g, ghb);
  k_tail<<<A_, 1024, 0, stream>>>(xl2_c, xr2g, ghb, agent_node, ncnt, hs, am,
                                  att2, b2, Wih, bih, Wa, ba, Wv, bv, out);
}